// Round 8
// baseline (301.564 us; speedup 1.0000x reference)
//
#include <hip/hip_runtime.h>
#include <hip/hip_bf16.h>

typedef __hip_bfloat16 bf16;
typedef __attribute__((ext_vector_type(8))) short short8;
typedef __attribute__((ext_vector_type(4))) float f32x4;
typedef unsigned short u16;
typedef unsigned int u32;

static __device__ __forceinline__ u16 f2bs(float f) {
    bf16 h = __float2bfloat16(f);
    return *reinterpret_cast<u16*>(&h);
}
static __device__ __forceinline__ float bs2f(u16 u) {
    union { float f; u32 i; } x; x.i = ((u32)u) << 16; return x.f;
}
static __device__ __forceinline__ uint4 pack8(const u16* p) {
    uint4 v;
    v.x = (u32)p[0] | ((u32)p[1] << 16);
    v.y = (u32)p[2] | ((u32)p[3] << 16);
    v.z = (u32)p[4] | ((u32)p[5] << 16);
    v.w = (u32)p[6] | ((u32)p[7] << 16);
    return v;
}

// =================== merged weight prep ===================
__device__ __forceinline__ void prep3_body(const float* __restrict__ w, short* __restrict__ wF,
                                           int C, int idx) {
    int j = idx & 7;
    int lane = (idx >> 3) & 63;
    int mt = (idx >> 9) & 3;
    int rest = idx >> 11;
    int pair = rest % 5;
    int bo = rest / 5;
    int nchunks = C / 16;
    int ch = bo % nchunks;
    int ocblk = bo / nchunks;
    int s = ((lane >> 4) * 8 + j);
    int tp = 2 * pair + (s >> 4);
    int ci = ch * 16 + (s & 15);
    int oc = ocblk * 64 + mt * 16 + (lane & 15);
    float v = (tp <= 8) ? w[((size_t)(oc * C + ci)) * 9 + tp] : 0.f;
    wF[idx] = (short)f2bs(v);
}
__device__ __forceinline__ void prep1_body(const float* __restrict__ w, short* __restrict__ wF,
                                           int Cin, int cioff, int nchunks, int idx) {
    int j = idx & 7;
    int lane = (idx >> 3) & 63;
    int mt = (idx >> 9) & 3;
    int bo = idx >> 11;
    int ch = bo % nchunks;
    int ocblk = bo / nchunks;
    int s = (lane >> 4) * 8 + j;
    int ci = cioff + ch * 32 + s;
    int oc = ocblk * 64 + mt * 16 + (lane & 15);
    wF[idx] = (short)f2bs(w[(size_t)oc * Cin + ci]);
}

__global__ __launch_bounds__(256) void prep_all(
        const float* __restrict__ wdwt, const float* __restrict__ widwt,
        const float* __restrict__ w2, const float* __restrict__ wproj,
        const float* __restrict__ w1,
        short* __restrict__ wF1, short* __restrict__ wF2c, short* __restrict__ wFk,
        short* __restrict__ wpF, short* __restrict__ wFq, float* __restrict__ scr) {
    int blk = blockIdx.x;
    int tid = threadIdx.x;
    if (blk < 2560) {
        prep3_body(wdwt, wF1, 256, blk * 256 + tid);
    } else if (blk < 2720) {
        prep3_body(widwt, wF2c, 64, (blk - 2560) * 256 + tid);
    } else if (blk < 2976) {
        prep1_body(w2, wFk, 256, 0, 8, (blk - 2720) * 256 + tid);
    } else if (blk < 2992) {
        prep1_body(wproj, wpF, 128, 64, 2, (blk - 2976) * 256 + tid);
    } else if (blk < 3008) {
        prep1_body(w1, wFq, 64, 0, 2, (blk - 2992) * 256 + tid);
    } else {
        for (int i = tid; i < 4864; i += 256) scr[i] = 0.f;
    }
}

// =================== fused Haar DWT + Q conv, 64-col tiles (1024 blocks) ===================
__global__ __launch_bounds__(256) void dwtq_kernel(
        const float* __restrict__ x, const short* __restrict__ wFq,
        const float* __restrict__ b1, short* __restrict__ d0, short* __restrict__ outQ) {
    __shared__ short ls[128 * 72];
    int tid = threadIdx.x;
    int lane = tid & 63, wv = tid >> 6;
    int q = lane >> 4, pl = lane & 15;
    int xq = blockIdx.x;
    int y2 = blockIdx.y;
    int b = blockIdx.z;
    int x0 = xq * 64;

    #pragma unroll
    for (int k2 = 0; k2 < 8; ++k2) {
        int u = k2 * 256 + tid;
        int ch = u & 63;
        int xu = (u >> 6) & 15;
        int r = (u >> 10) & 1;
        float4 v = *(const float4*)(x + (((size_t)(b * 64 + ch) * 256 + (2 * y2 + r))) * 256 + x0 + xu * 4);
        ls[(r * 64 + xu * 4 + 0) * 72 + ch] = (short)f2bs(v.x);
        ls[(r * 64 + xu * 4 + 1) * 72 + ch] = (short)f2bs(v.y);
        ls[(r * 64 + xu * 4 + 2) * 72 + ch] = (short)f2bs(v.z);
        ls[(r * 64 + xu * 4 + 3) * 72 + ch] = (short)f2bs(v.w);
    }
    __syncthreads();

    // ---- Q conv: wave covers px [wv*32, +32) of the 128 staged px ----
    f32x4 acc[4][2];
    #pragma unroll
    for (int mt = 0; mt < 4; ++mt)
        #pragma unroll
        for (int nt = 0; nt < 2; ++nt)
            acc[mt][nt] = (f32x4){0.f, 0.f, 0.f, 0.f};
    #pragma unroll
    for (int chk = 0; chk < 2; ++chk) {
        short8 af[4];
        #pragma unroll
        for (int mt = 0; mt < 4; ++mt)
            af[mt] = *(const short8*)(wFq + (chk * 4 + mt) * 512 + lane * 8);
        #pragma unroll
        for (int nt = 0; nt < 2; ++nt) {
            int p = wv * 32 + nt * 16 + pl;
            short8 bfr = *(const short8*)(ls + p * 72 + chk * 32 + q * 8);
            #pragma unroll
            for (int mt = 0; mt < 4; ++mt)
                acc[mt][nt] = __builtin_amdgcn_mfma_f32_16x16x32_bf16(af[mt], bfr, acc[mt][nt], 0, 0, 0);
        }
    }
    #pragma unroll
    for (int mt = 0; mt < 4; ++mt) {
        int ocb = mt * 16 + q * 4;
        float4 bi = *(const float4*)(b1 + ocb);
        float bia[4] = {bi.x, bi.y, bi.z, bi.w};
        #pragma unroll
        for (int nt = 0; nt < 2; ++nt) {
            int p = wv * 32 + nt * 16 + pl;
            int n = (2 * y2 + (p >> 6)) * 256 + x0 + (p & 63);
            #pragma unroll
            for (int r = 0; r < 4; ++r)
                outQ[((size_t)(b * 64 + ocb + r)) * 65536 + n] = (short)f2bs(acc[mt][nt][r] + bia[r]);
        }
    }

    // ---- Haar DWT: 32 dwt px x 64 ch -> D0 cl ----
    int xl = tid >> 3;
    int sub = tid & 7;
    int c0 = sub * 8;
    u16 obuf[4][8];
    #pragma unroll
    for (int cl = 0; cl < 8; ++cl) {
        int c = c0 + cl;
        float a  = bs2f(ls[(2 * xl) * 72 + c]);
        float bb = bs2f(ls[(2 * xl + 1) * 72 + c]);
        float c2 = bs2f(ls[(64 + 2 * xl) * 72 + c]);
        float dd = bs2f(ls[(64 + 2 * xl + 1) * 72 + c]);
        obuf[0][cl] = f2bs((a - bb + c2 - dd) * 0.5f);  // lh
        obuf[1][cl] = f2bs((a + bb - c2 - dd) * 0.5f);  // hl
        obuf[2][cl] = f2bs((a - bb - c2 + dd) * 0.5f);  // hh
        obuf[3][cl] = f2bs((a + bb + c2 + dd) * 0.5f);  // ll
    }
    int xd = xq * 32 + xl;
    size_t P = ((size_t)(b * 128 + y2) * 128 + xd) * 256;
    #pragma unroll
    for (int g = 0; g < 4; ++g)
        *(uint4*)&d0[P + g * 64 + c0] = pack8(&obuf[g][0]);
}

// =================== Haar IDWT ===================
__global__ __launch_bounds__(256) void idwt_kernel(const short* __restrict__ d1, short* __restrict__ i0) {
    int tid = threadIdx.x;
    int lane = tid & 63;
    int p = blockIdx.x * 4 + (tid >> 6);
    int b = p >> 14, m = p & 16383;
    ushort4 v = *(const ushort4*)(d1 + ((size_t)(b * 16384 + m)) * 256 + 4 * lane);
    float yl = bs2f(v.x), lh = bs2f(v.y), hl = bs2f(v.z), hh = bs2f(v.w);
    float a_ = (yl + lh + hl + hh) * 0.5f;
    float b_ = (yl - lh + hl - hh) * 0.5f;
    float c_ = (yl + lh - hl - hh) * 0.5f;
    float d_ = (yl - lh - hl + hh) * 0.5f;
    int y = m >> 7, xx = m & 127;
    u16* o = (u16*)i0;
    size_t base = ((size_t)(b * 256 + 2 * y) * 256 + 2 * xx) * 64 + lane;
    o[base] = f2bs(a_);
    o[base + 64] = f2bs(b_);
    o[base + 256 * 64] = f2bs(c_);
    o[base + 256 * 64 + 64] = f2bs(d_);
}

// =================== 3x3 conv v4: tunable wave tile ===================
template <int C, int MT, int NT, int WPG>
__global__ __launch_bounds__(256) void conv3_v4(
        const short* __restrict__ in, const short* __restrict__ wF,
        const float* __restrict__ bias, short* __restrict__ out,
        int H, int W) {
    constexpr int NPX = WPG * NT * 16;
    constexpr int Wp = NPX + 2;
    constexpr int NCH = C / 16;
    constexpr int OCB = (4 / WPG) * MT * 16;
    constexpr int NOCB = C / OCB;
    constexpr int UNITS = 3 * Wp * 2;
    constexpr int UPT = (UNITS + 255) / 256;
    constexpr int BUFSZ = 3 * Wp * 16;
    extern __shared__ __align__(16) short inS[];

    int tid = threadIdx.x;
    int lane = tid & 63, wv = tid >> 6;
    int q = lane >> 4, pl = lane & 15;
    int obi = blockIdx.x % NOCB;
    int pxi = blockIdx.x / NOCB;
    int ocg = obi * (4 / WPG) + wv / WPG;
    int pxoff = (wv % WPG) * NT * 16;
    int x0 = pxi * NPX;
    int y = blockIdx.y;
    int b = blockIdx.z;

    int gbase[UPT];
    int ldsoff[UPT];
    #pragma unroll
    for (int k2 = 0; k2 < UPT; ++k2) {
        int u = k2 * 256 + tid;
        if (u < UNITS) {
            int r = u / (Wp * 2);
            int rem = u - r * (Wp * 2);
            int px = rem >> 1, hf = rem & 1;
            int ry = y - 1 + r;
            if (ry < 0) ry = 1;
            if (ry >= H) ry = H - 2;
            int rx = x0 - 1 + px;
            if (rx < 0) rx = 1;
            if (rx >= W) rx = W - 2;
            gbase[k2] = ((b * H + ry) * W + rx) * C + hf * 8;
            ldsoff[k2] = (r * Wp + px) * 16 + hf * 8;
        } else { gbase[k2] = 0; ldsoff[k2] = -1; }
    }

    f32x4 acc[MT][NT];
    #pragma unroll
    for (int mt = 0; mt < MT; ++mt)
        #pragma unroll
        for (int nt = 0; nt < NT; ++nt)
            acc[mt][nt] = (f32x4){0.f, 0.f, 0.f, 0.f};

    uint4 pf[UPT];
    #pragma unroll
    for (int k2 = 0; k2 < UPT; ++k2)
        if (ldsoff[k2] >= 0) pf[k2] = *(const uint4*)(in + gbase[k2]);
    #pragma unroll
    for (int k2 = 0; k2 < UPT; ++k2)
        if (ldsoff[k2] >= 0) *(uint4*)(inS + ldsoff[k2]) = pf[k2];
    __syncthreads();

    #pragma unroll 1
    for (int ch = 0; ch < NCH; ++ch) {
        const short* buf = inS + (ch & 1) * BUFSZ;
        short* nbuf = inS + ((ch + 1) & 1) * BUFSZ;
        bool more = (ch + 1 < NCH);
        if (more) {
            #pragma unroll
            for (int k2 = 0; k2 < UPT; ++k2)
                if (ldsoff[k2] >= 0) pf[k2] = *(const uint4*)(in + gbase[k2] + (ch + 1) * 16);
        }
        short8 wreg[5][MT];
        #pragma unroll
        for (int pr = 0; pr < 5; ++pr)
            #pragma unroll
            for (int mt = 0; mt < MT; ++mt) {
                int g16 = ocg * MT + mt;
                wreg[pr][mt] = *(const short8*)(wF +
                    ((size_t)(((g16 >> 2) * NCH + ch) * 5 + pr) * 4 + (g16 & 3)) * 512 + lane * 8);
            }
        #pragma unroll
        for (int pr = 0; pr < 5; ++pr) {
            int t1 = 2 * pr + (q >> 1);
            if (t1 > 8) t1 = 8;
            int ti = (t1 >= 6) ? 2 : ((t1 >= 3) ? 1 : 0);
            int tj = t1 - ti * 3;
            #pragma unroll
            for (int nt = 0; nt < NT; ++nt) {
                int i = pxoff + nt * 16 + pl + tj;
                short8 bfr = *(const short8*)(buf + (ti * Wp + i) * 16 + (q & 1) * 8);
                #pragma unroll
                for (int mt = 0; mt < MT; ++mt)
                    acc[mt][nt] = __builtin_amdgcn_mfma_f32_16x16x32_bf16(wreg[pr][mt], bfr, acc[mt][nt], 0, 0, 0);
            }
        }
        if (more) {
            #pragma unroll
            for (int k2 = 0; k2 < UPT; ++k2)
                if (ldsoff[k2] >= 0) *(uint4*)(nbuf + ldsoff[k2]) = pf[k2];
            __syncthreads();
        }
    }

    #pragma unroll
    for (int mt = 0; mt < MT; ++mt) {
        int ocb = ocg * MT * 16 + mt * 16 + q * 4;
        float4 bi = *(const float4*)(bias + ocb);
        float bia[4] = {bi.x, bi.y, bi.z, bi.w};
        #pragma unroll
        for (int nt = 0; nt < NT; ++nt) {
            int xl = x0 + pxoff + nt * 16 + pl;
            ushort4 pk;
            float v0 = acc[mt][nt][0] + bia[0]; pk.x = f2bs(v0 >= 0.f ? v0 : 0.01f * v0);
            float v1 = acc[mt][nt][1] + bia[1]; pk.y = f2bs(v1 >= 0.f ? v1 : 0.01f * v1);
            float v2 = acc[mt][nt][2] + bia[2]; pk.z = f2bs(v2 >= 0.f ? v2 : 0.01f * v2);
            float v3 = acc[mt][nt][3] + bia[3]; pk.w = f2bs(v3 >= 0.f ? v3 : 0.01f * v3);
            *(ushort4*)(out + (((size_t)(b * H + y)) * W + xl) * C + ocb) = pk;
        }
    }
}

// =================== K conv 1x1 MFMA, 128-px tiles (1024 blocks) ===================
__global__ __launch_bounds__(256) void kconv_mfma(
        const short* __restrict__ in, const short* __restrict__ wF,
        const float* __restrict__ bias, short* __restrict__ outK) {
    __shared__ short inS[4096];
    int tid = threadIdx.x;
    int lane = tid & 63, wv = tid >> 6;
    int q = lane >> 4, pl = lane & 15;
    int ocblk = blockIdx.x;
    int m0 = blockIdx.y * 128;
    int b = blockIdx.z;
    int px0w = wv * 32;
    f32x4 acc[4][2];
    #pragma unroll
    for (int mt = 0; mt < 4; ++mt)
        #pragma unroll
        for (int nt = 0; nt < 2; ++nt)
            acc[mt][nt] = (f32x4){0.f, 0.f, 0.f, 0.f};

    for (int ch = 0; ch < 8; ++ch) {
        if (ch) __syncthreads();
        const short* src = in + ((size_t)(b * 16384 + m0)) * 256 + ch * 32;
        #pragma unroll
        for (int k2 = 0; k2 < 2; ++k2) {
            int t = k2 * 256 + tid;
            int pix = t >> 2, hf = t & 3;
            *(uint4*)(inS + pix * 32 + hf * 8) = *(const uint4*)(src + (size_t)pix * 256 + hf * 8);
        }
        short8 af[4];
        #pragma unroll
        for (int mt = 0; mt < 4; ++mt)
            af[mt] = *(const short8*)(wF + ((size_t)(ocblk * 8 + ch)) * 2048 + mt * 512 + lane * 8);
        __syncthreads();
        #pragma unroll
        for (int nt = 0; nt < 2; ++nt) {
            short8 bfr = *(const short8*)(inS + (px0w + nt * 16 + pl) * 32 + q * 8);
            #pragma unroll
            for (int mt = 0; mt < 4; ++mt)
                acc[mt][nt] = __builtin_amdgcn_mfma_f32_16x16x32_bf16(af[mt], bfr, acc[mt][nt], 0, 0, 0);
        }
    }
    #pragma unroll
    for (int mt = 0; mt < 4; ++mt) {
        int ocb = ocblk * 64 + mt * 16 + q * 4;
        float4 bi = *(const float4*)(bias + ocb);
        float bia[4] = {bi.x, bi.y, bi.z, bi.w};
        #pragma unroll
        for (int nt = 0; nt < 2; ++nt) {
            int n = m0 + px0w + nt * 16 + pl;
            #pragma unroll
            for (int r = 0; r < 4; ++r) {
                int co = ocb + r;
                outK[((size_t)(b * 64 + (co >> 2))) * 65536 + (co & 3) * 16384 + n] =
                    (short)f2bs(acc[mt][nt][r] + bia[r]);
            }
        }
    }
}

// =================== Gram via MFMA: 256-wide slices (512 blocks) ===================
__global__ __launch_bounds__(256) void gram_mfma(
        const short* __restrict__ Q, const short* __restrict__ K,
        float* __restrict__ qss, float* __restrict__ kss, float* __restrict__ gram) {
    int tid = threadIdx.x;
    int lane = tid & 63, h = tid >> 6;
    int q = lane >> 4, m = lane & 15;
    int b = blockIdx.y;
    int n0 = blockIdx.x * 256;
    const short* qrow = Q + ((size_t)(b * 64 + h * 16 + m)) * 65536 + n0 + q * 8;
    const short* krow = K + ((size_t)(b * 64 + h * 16 + m)) * 65536 + n0 + q * 8;
    f32x4 acc = (f32x4){0.f, 0.f, 0.f, 0.f};
    float sq = 0.f, sk = 0.f;
    #pragma unroll
    for (int it = 0; it < 8; ++it) {
        short8 aq = *(const short8*)(qrow + it * 32);
        short8 ak = *(const short8*)(krow + it * 32);
        acc = __builtin_amdgcn_mfma_f32_16x16x32_bf16(aq, ak, acc, 0, 0, 0);
        #pragma unroll
        for (int j = 0; j < 8; ++j) {
            float fq = bs2f((u16)aq[j]);
            float fk = bs2f((u16)ak[j]);
            sq += fq * fq;
            sk += fk * fk;
        }
    }
    sq += __shfl_xor(sq, 16); sq += __shfl_xor(sq, 32);
    sk += __shfl_xor(sk, 16); sk += __shfl_xor(sk, 32);
    if (q == 0) {
        atomicAdd(&qss[b * 64 + h * 16 + m], sq);
        atomicAdd(&kss[b * 64 + h * 16 + m], sk);
    }
    #pragma unroll
    for (int r = 0; r < 4; ++r) {
        int c = q * 4 + r;
        atomicAdd(&gram[b * 1024 + h * 256 + c * 16 + m], acc[r]);
    }
}

// =================== fold v3: inline softmax + fold (128 blocks) ===================
__global__ __launch_bounds__(256) void fold_v3(
        const float* __restrict__ gram, const float* __restrict__ qss,
        const float* __restrict__ kss, const float* __restrict__ temp,
        const float* __restrict__ w3, const float* __restrict__ b3,
        const float* __restrict__ wproj,
        short* __restrict__ WfoldF, float* __restrict__ bfold) {
    __shared__ float attn_s[1024];
    __shared__ float wp_s[64][65];
    __shared__ float Aeff_s[64][17];
    __shared__ float beff[64];
    __shared__ float rmax[64], rsum[64];
    int bt = blockIdx.y;
    int b = bt >> 2, t = bt & 3;
    int ci0 = blockIdx.x * 16;
    int tid = threadIdx.x;
    #pragma unroll
    for (int k = 0; k < 4; ++k) {
        int el = tid + k * 256;
        int r = el >> 4, d = el & 15, h = r >> 4;
        float qn = fmaxf(sqrtf(qss[b * 64 + r]), 1e-12f);
        float kn = fmaxf(sqrtf(kss[b * 64 + h * 16 + d]), 1e-12f);
        attn_s[el] = gram[b * 1024 + el] / (qn * kn) * temp[h];
    }
    #pragma unroll
    for (int i = 0; i < 16; ++i) {
        int idx = tid + i * 256;
        wp_s[idx >> 6][idx & 63] = wproj[(idx >> 6) * 128 + (idx & 63)];
    }
    __syncthreads();
    if (tid < 64) {
        float mm = -1e30f;
        for (int d = 0; d < 16; ++d) mm = fmaxf(mm, attn_s[tid * 16 + d]);
        rmax[tid] = mm;
    }
    __syncthreads();
    #pragma unroll
    for (int k = 0; k < 4; ++k) {
        int el = tid + k * 256;
        attn_s[el] = expf(attn_s[el] - rmax[el >> 4]);
    }
    __syncthreads();
    if (tid < 64) {
        float s = 0.f;
        for (int d = 0; d < 16; ++d) s += attn_s[tid * 16 + d];
        rsum[tid] = s;
    }
    __syncthreads();
    #pragma unroll
    for (int k = 0; k < 4; ++k) {
        int el = tid + k * 256;
        attn_s[el] /= rsum[el >> 4];
    }
    __syncthreads();
    #pragma unroll
    for (int pass = 0; pass < 4; ++pass) {
        int el = pass * 256 + tid;
        int C = el >> 4, ci_l = el & 15;
        int h = C >> 4, c = C & 15;
        float s = 0.f;
        #pragma unroll
        for (int d = 0; d < 16; ++d)
            s += attn_s[h * 256 + c * 16 + d] * w3[(size_t)(4 * (h * 16 + d) + t) * 256 + ci0 + ci_l];
        Aeff_s[C][ci_l] = s;
    }
    if (blockIdx.x == 0 && tid < 64) {
        int h = tid >> 4, c = tid & 15;
        float s = 0.f;
        #pragma unroll
        for (int d = 0; d < 16; ++d)
            s += attn_s[h * 256 + c * 16 + d] * b3[4 * (h * 16 + d) + t];
        beff[tid] = s;
    }
    __syncthreads();
    #pragma unroll
    for (int pass = 0; pass < 4; ++pass) {
        int el = pass * 256 + tid;
        int ci_l = el >> 6, co = el & 63;
        float s = 0.f;
        #pragma unroll
        for (int C = 0; C < 64; ++C) s += wp_s[co][C] * Aeff_s[C][ci_l];
        int ci = ci0 + ci_l;
        int chk = ci >> 5;
        int s5 = ci & 31;
        int j = s5 & 7;
        int lane2 = (((s5 >> 3) << 4)) | (co & 15);
        int mt = co >> 4;
        WfoldF[(((size_t)(bt * 8 + chk) * 4 + mt)) * 512 + lane2 * 8 + j] = (short)f2bs(s);
    }
    if (blockIdx.x == 0 && tid < 64) {
        float s = 0.f;
        #pragma unroll
        for (int C = 0; C < 64; ++C) s += wp_s[tid][C] * beff[C];
        bfold[bt * 64 + tid] = s;
    }
}

// =================== final: 128-px tiles (512 blocks), fp32 out ===================
__global__ __launch_bounds__(256) void final_mfma(
        const short* __restrict__ D1, const short* __restrict__ I2,
        const short* __restrict__ WfoldF, const short* __restrict__ wpF,
        const float* __restrict__ bfold, float* __restrict__ out) {
    __shared__ short inS[4096];
    int tid = threadIdx.x;
    int lane = tid & 63, wv = tid >> 6;
    int q = lane >> 4, pl = lane & 15;
    int n0 = blockIdx.x * 128;
    int b = blockIdx.y;
    int t = n0 >> 14, m0 = n0 & 16383, bt = b * 4 + t;
    int px0w = wv * 32;
    f32x4 acc[4][2];
    #pragma unroll
    for (int mt = 0; mt < 4; ++mt) {
        float4 bf4 = *(const float4*)(bfold + bt * 64 + mt * 16 + q * 4);
        #pragma unroll
        for (int nt = 0; nt < 2; ++nt)
            acc[mt][nt] = (f32x4){bf4.x, bf4.y, bf4.z, bf4.w};
    }
    for (int ch = 0; ch < 8; ++ch) {
        if (ch) __syncthreads();
        const short* src = D1 + ((size_t)(b * 16384 + m0)) * 256 + ch * 32;
        #pragma unroll
        for (int k2 = 0; k2 < 2; ++k2) {
            int tt = k2 * 256 + tid;
            int pix = tt >> 2, hf = tt & 3;
            *(uint4*)(inS + pix * 32 + hf * 8) = *(const uint4*)(src + (size_t)pix * 256 + hf * 8);
        }
        short8 af[4];
        #pragma unroll
        for (int mt = 0; mt < 4; ++mt)
            af[mt] = *(const short8*)(WfoldF + ((size_t)(bt * 8 + ch)) * 2048 + mt * 512 + lane * 8);
        __syncthreads();
        #pragma unroll
        for (int nt = 0; nt < 2; ++nt) {
            short8 bfr = *(const short8*)(inS + (px0w + nt * 16 + pl) * 32 + q * 8);
            #pragma unroll
            for (int mt = 0; mt < 4; ++mt)
                acc[mt][nt] = __builtin_amdgcn_mfma_f32_16x16x32_bf16(af[mt], bfr, acc[mt][nt], 0, 0, 0);
        }
    }
    for (int ch = 0; ch < 2; ++ch) {
        __syncthreads();
        const short* src = I2 + ((size_t)(b * 65536 + n0)) * 64 + ch * 32;
        #pragma unroll
        for (int k2 = 0; k2 < 2; ++k2) {
            int tt = k2 * 256 + tid;
            int pix = tt >> 2, hf = tt & 3;
            *(uint4*)(inS + pix * 32 + hf * 8) = *(const uint4*)(src + (size_t)pix * 64 + hf * 8);
        }
        short8 af[4];
        #pragma unroll
        for (int mt = 0; mt < 4; ++mt)
            af[mt] = *(const short8*)(wpF + (size_t)ch * 2048 + mt * 512 + lane * 8);
        __syncthreads();
        #pragma unroll
        for (int nt = 0; nt < 2; ++nt) {
            short8 bfr = *(const short8*)(inS + (px0w + nt * 16 + pl) * 32 + q * 8);
            #pragma unroll
            for (int mt = 0; mt < 4; ++mt)
                acc[mt][nt] = __builtin_amdgcn_mfma_f32_16x16x32_bf16(af[mt], bfr, acc[mt][nt], 0, 0, 0);
        }
    }
    #pragma unroll
    for (int mt = 0; mt < 4; ++mt) {
        #pragma unroll
        for (int nt = 0; nt < 2; ++nt) {
            int n = n0 + px0w + nt * 16 + pl;
            #pragma unroll
            for (int r = 0; r < 4; ++r) {
                int co = mt * 16 + q * 4 + r;
                out[((size_t)(b * 64 + co)) * 65536 + n] = acc[mt][nt][r];
            }
        }
    }
}

extern "C" void kernel_launch(void* const* d_in, const int* in_sizes, int n_in,
                              void* d_out, int out_size, void* d_ws, size_t ws_size,
                              hipStream_t stream) {
    const float* x     = (const float*)d_in[0];
    const float* temp  = (const float*)d_in[1];
    const float* w1    = (const float*)d_in[2];
    const float* b1    = (const float*)d_in[3];
    const float* w2    = (const float*)d_in[4];
    const float* b2    = (const float*)d_in[5];
    const float* w3    = (const float*)d_in[6];
    const float* b3    = (const float*)d_in[7];
    const float* wdwt  = (const float*)d_in[8];
    const float* bdwt  = (const float*)d_in[9];
    const float* widwt = (const float*)d_in[10];
    const float* bidwt = (const float*)d_in[11];
    const float* wproj = (const float*)d_in[12];
    float* out = (float*)d_out;

    char* W8 = (char*)d_ws;
    const size_t SLOT = 16777216;
    short* slotA = (short*)(W8);              // D0 -> I0
    short* slotB = (short*)(W8 + SLOT);       // D1
    short* slotC = (short*)(W8 + 2 * SLOT);   // Qb -> I2
    short* slotD = (short*)(W8 + 3 * SLOT);   // Kb
    char* P = W8 + 4 * SLOT;
    short* wF1    = (short*)P; P += 2 * 655360;
    short* wF2c   = (short*)P; P += 2 * 40960;
    short* wFk    = (short*)P; P += 2 * 65536;
    short* wpF    = (short*)P; P += 2 * 4096;
    short* wFq    = (short*)P; P += 2 * 4096;
    short* WfoldF = (short*)P; P += 2 * 131072;
    float* scr    = (float*)P;
    float* qss   = scr;
    float* kss   = scr + 128;
    float* gram  = scr + 256;
    float* bfold = scr + 4352;

    prep_all<<<3009, 256, 0, stream>>>(wdwt, widwt, w2, wproj, w1,
                                       wF1, wF2c, wFk, wpF, wFq, scr);

    // fused DWT + Q conv: D0 -> slotA, Qb -> slotC
    dwtq_kernel<<<dim3(4, 128, 2), 256, 0, stream>>>(x, wFq, b1, slotA, slotC);

    // DWT-branch 3x3 conv (128oc x 64px blocks, 1024 blocks)
    conv3_v4<256, 2, 4, 1><<<dim3(4, 128, 2), 256, 12672, stream>>>(slotA, wF1, bdwt, slotB, 128, 128);

    // K conv + gram
    kconv_mfma<<<dim3(4, 128, 2), 256, 0, stream>>>(slotB, wFk, b2, slotD);
    gram_mfma<<<dim3(256, 2), 256, 0, stream>>>(slotC, slotD, qss, kss, gram);

    // IDWT branch (64oc x 128px blocks, 1024 blocks)
    idwt_kernel<<<8192, 256, 0, stream>>>(slotB, slotA);
    conv3_v4<64, 4, 2, 4><<<dim3(2, 256, 2), 256, 24960, stream>>>(slotA, wF2c, bidwt, slotC, 256, 256);

    // softmax + fold (fused)
    fold_v3<<<dim3(16, 8), 256, 0, stream>>>(gram, qss, kss, temp, w3, b3, wproj, WfoldF, bfold);

    // fused (attn·V + proj) + idwt-branch proj  [512 blocks: 65536 px / 128-px tiles]
    final_mfma<<<dim3(512, 2), 256, 0, stream>>>(slotB, slotC, WfoldF, wpF, bfold, out);
}